// Round 6
// baseline (84.068 us; speedup 1.0000x reference)
//
#include <hip/hip_runtime.h>
#include <stdint.h>

#define NQ 14
#define DIM 16384
#define NL 6
#define NBATCH 1024
#define PI_F 3.14159265358979323846f
#define BLOCK 256

// ================= constexpr GF(2) circuit algebra =================
// Verified (round 2 absmax 0.0; round 5 absmax 0.0).  CNOT chain = I+S.
// After l chains, gate on bit p pairs i with i^mcol(l,p); side-0 selected by
// parity(i & grow(l,p)).  Lucas: C(l,k) odd iff (k & ~l)==0.
constexpr uint32_t mcol(int l, int p) {          // column p of (I+S)^l
    uint32_t m = 0;
    for (int k = 0; k <= p; ++k) if ((k & ~l) == 0) m ^= 1u << (p - k);
    return m;
}
constexpr uint32_t grow(int l, int p) {          // row p of U^l = (I+S)^(16-l)
    uint32_t g = 0;
    const int e = 16 - l;
    for (int k = 0; k + p < NQ; ++k) if ((k & ~e) == 0) g ^= 1u << (p + k);
    return g;
}
constexpr uint32_t popb(uint32_t x) { uint32_t c = 0; while (x) { c += x & 1u; x >>= 1; } return c; }
constexpr int msbit(uint32_t m) { int b = 0; while (m >> (b + 1)) ++b; return b; }
// bank swizzle on the COMPRESSED (bit1-removed) index; preserves bits 0..1
constexpr uint32_t SWC(uint32_t j) { return j ^ (((j >> 7) & 7u) << 2); }

template<int GRP> constexpr int pbase()  { return GRP == 0 ? 0 : (GRP == 1 ? 6 : 10); }
template<int GRP> constexpr int ngates() { return GRP == 0 ? 6 : 4; }

// phase basis: {e0,e1} + 4 "hi" vectors (4-aligned)
template<int L, int GRP, int J> constexpr uint32_t mhv() {
    if constexpr (GRP == 0) return 4u << J;                       // e2..e5
    else return mcol(L, pbase<GRP>() + J) & ~3u;                  // gate hi parts
}
template<int L, int GRP, int K> constexpr uint32_t rmv() {        // register-space mask
    constexpr int p = pbase<GRP>() + K;
    if constexpr (GRP == 0) return mcol(L, p);                    // identity basis
    else return (4u << K) | (mcol(L, p) & 3u);
}
constexpr uint32_t mreg(uint32_t r, uint32_t m0, uint32_t m1, uint32_t m2, uint32_t m3) {
    uint32_t M = r & 3u;
    if (r & 4u)  M ^= m0;
    if (r & 8u)  M ^= m1;
    if (r & 16u) M ^= m2;
    if (r & 32u) M ^= m3;
    return M;
}
constexpr uint64_t sgnw_f(uint32_t m0, uint32_t m1, uint32_t m2, uint32_t m3, uint32_t g) {
    uint64_t w = 0;
    for (uint32_t r = 0; r < 64; ++r)
        w |= (uint64_t)(popb(mreg(r, m0, m1, m2, m3) & g) & 1u) << r;
    return w;
}
template<int GRP> constexpr uint32_t cg_of(uint32_t g) {          // tid-parity mask
    if constexpr (GRP == 0) return (g >> 6) & 0xFFu;                              // comp = e6..e13
    else if constexpr (GRP == 1) return ((g >> 2) & 0xFu) | (((g >> 10) & 0xFu) << 4); // e2..e5,e10..e13
    else return (g >> 2) & 0xFFu;                                                 // e2..e9
}
constexpr bool indep6(uint32_t a, uint32_t b, uint32_t c, uint32_t d) {
    uint32_t v[6] = {1u, 2u, a, b, c, d};
    int rank = 0;
    for (int bit = 13; bit >= 0; --bit) {
        int piv = -1;
        for (int i = rank; i < 6; ++i) if ((v[i] >> bit) & 1) { piv = i; break; }
        if (piv < 0) continue;
        uint32_t t = v[piv]; v[piv] = v[rank]; v[rank] = t;
        for (int i = 0; i < 6; ++i) if (i != rank && ((v[i] >> bit) & 1)) v[i] ^= t;
        ++rank;
    }
    return rank == 6;
}

// RAW thread-base element index per layout (un-swizzled)
template<int GRP> __device__ __forceinline__ uint32_t btb_of(uint32_t tid) {
    if constexpr (GRP == 0) return tid << 6;
    else if constexpr (GRP == 1) return ((tid & 15u) << 2) | ((tid & 0xF0u) << 6);
    else return tid << 2;
}

// ================= register-space gate (all compile-time) =================
template<uint32_t RM, uint64_t SG>
__device__ __forceinline__ void gate64(float (&rs)[64], float c, float svp) {
    constexpr uint32_t HB = 1u << msbit(RM);
#pragma unroll
    for (uint32_t r = 0; r < 64; ++r) {
        if ((r & HB) == 0u) {
            const float sv = ((SG >> r) & 1ull) ? -svp : svp;   // compile-time select
            const float u = rs[r], v = rs[r ^ RM];
            const float t0 = sv * v;
            const float t1 = sv * u;
            rs[r]      = fmaf(c, u, -t0);   // side0' = c*s0 - s*s1
            rs[r ^ RM] = fmaf(c, v,  t1);   // side1' = c*s1 + s*s0
        }
    }
}

template<int L, int GRP, int K>
__device__ __forceinline__ void gates_rec(float (&rs)[64], const float* __restrict__ cst,
                                          const float* __restrict__ snt, int tid) {
    if constexpr (K < ngates<GRP>()) {
        constexpr int p = pbase<GRP>() + K;
        constexpr uint32_t g  = grow(L, p);
        constexpr uint32_t RM = rmv<L, GRP, K>();
        constexpr uint64_t SG = sgnw_f(mhv<L,GRP,0>(), mhv<L,GRP,1>(), mhv<L,GRP,2>(), mhv<L,GRP,3>(), g);
        constexpr uint32_t CG = cg_of<GRP>(g);
        constexpr int widx = (L - 1) * NQ + (13 - p);
        const float c = cst[widx];
        const float s = snt[widx];
        const float svp = (__popc((uint32_t)tid & CG) & 1) ? -s : s;
        gate64<RM, SG>(rs, c, svp);
        gates_rec<L, GRP, K + 1>(rs, cst, snt, tid);
    }
}

template<int L, int GRP>
__device__ __forceinline__ void run_gates(float (&rs)[64], const float* __restrict__ cst,
                                          const float* __restrict__ snt, int tid) {
    static_assert(indep6(mhv<L,GRP,0>(), mhv<L,GRP,1>(), mhv<L,GRP,2>(), mhv<L,GRP,3>()), "basis rank");
    gates_rec<L, GRP, 0>(rs, cst, snt, tid);
}

// ---- split-transit IO: HALF=0 -> quad elements d=0,1 (bit1=0); HALF=1 -> d=2,3 ----
// compressed slot j = (E>>1) | e0 is layout-independent; both halves share j-space in time.
template<int L, int GRP, int HALF, bool WR>
__device__ __forceinline__ void lds_half(float (&rs)[64], float* bt, int tid) {
    constexpr uint32_t m0 = mhv<L,GRP,0>(), m1 = mhv<L,GRP,1>(), m2 = mhv<L,GRP,2>(), m3 = mhv<L,GRP,3>();
    const uint32_t btb = btb_of<GRP>((uint32_t)tid);
#pragma unroll
    for (uint32_t gq = 0; gq < 16; ++gq) {
        const uint32_t K = ((gq & 1) ? m0 : 0u) ^ ((gq & 2) ? m1 : 0u) ^
                           ((gq & 4) ? m2 : 0u) ^ ((gq & 8) ? m3 : 0u);
        const uint32_t a = SWC((btb ^ K) >> 1);                 // 2-aligned, folds
        if constexpr (WR) {
            float2 v;
            v.x = rs[gq * 4 + HALF * 2 + 0];
            v.y = rs[gq * 4 + HALF * 2 + 1];
            *reinterpret_cast<float2*>(bt + a) = v;
        } else {
            const float2 v = *reinterpret_cast<const float2*>(bt + a);
            rs[gq * 4 + HALF * 2 + 0] = v.x;
            rs[gq * 4 + HALF * 2 + 1] = v.y;
        }
    }
}

template<int Lo, int Go, int Ln, int Gn>
__device__ __forceinline__ void transition(float (&rs)[64], float* bt, int tid) {
    __syncthreads();                          // prior reads of bt complete
    lds_half<Lo, Go, 0, true >(rs, bt, tid);  // write half0 (old layout)
    __syncthreads();
    lds_half<Ln, Gn, 0, false>(rs, bt, tid);  // read half0 (new layout)
    __syncthreads();
    lds_half<Lo, Go, 1, true >(rs, bt, tid);  // write half1
    __syncthreads();
    lds_half<Ln, Gn, 1, false>(rs, bt, tid);  // read half1
}

// ================= prepass: min/scale + gate cos/sin tables =================
__global__ __launch_bounds__(256) void qs_norm_kernel(const float* __restrict__ x,
                                                      const float* __restrict__ w,
                                                      float* __restrict__ ws) {
    const int q = blockIdx.x;
    const int tid = threadIdx.x;
    float mn = 3.0e38f, mx = -3.0e38f;
    for (int r = tid; r < NBATCH; r += 256) {
        const float v = x[r * NQ + q];
        mn = fminf(mn, v);
        mx = fmaxf(mx, v);
    }
#pragma unroll
    for (int off = 32; off > 0; off >>= 1) {
        mn = fminf(mn, __shfl_down(mn, off));
        mx = fmaxf(mx, __shfl_down(mx, off));
    }
    __shared__ float smn[4], smx[4];
    const int wid = tid >> 6, lane = tid & 63;
    if (lane == 0) { smn[wid] = mn; smx[wid] = mx; }
    __syncthreads();
    if (tid == 0) {
        mn = fminf(fminf(smn[0], smn[1]), fminf(smn[2], smn[3]));
        mx = fmaxf(fmaxf(smx[0], smx[1]), fmaxf(smx[2], smx[3]));
        ws[q] = mn;
        ws[NQ + q] = PI_F / (mx - mn + 1e-8f);
    }
    if (blockIdx.x == 0) {
        for (int t = tid; t < (NL - 1) * NQ; t += 256) {
            const float h = 0.5f * w[NQ + t];
            ws[32 + t]  = cosf(h);
            ws[112 + t] = sinf(h);
        }
    }
}

// ================= main: one block per batch element =================
__global__ __launch_bounds__(BLOCK) void qs_main_kernel(
        const float* __restrict__ x, const float* __restrict__ w,
        const float* __restrict__ nrm, const float* __restrict__ cst,
        const float* __restrict__ snt, float* __restrict__ out) {
    __shared__ __align__(16) float bt[DIM / 2];       // 32 KB transit buffer
    __shared__ float sciL[NQ], ssiL[NQ];
    __shared__ float red0[4], red1[4];
    const int tid = threadIdx.x;
    const int b = blockIdx.x;

    // merged encoding + layer-0 angles, computed ONCE per block (broadcast via LDS)
    if (tid < NQ) {
        const float ang = (x[b * NQ + tid] - nrm[tid]) * nrm[NQ + tid] + w[tid];
        const float h = 0.5f * ang;
        sciL[tid] = cosf(h);
        ssiL[tid] = sinf(h);
    }
    __syncthreads();

    // product state directly in registers, layout (1,0): i=(tid<<6)|r, bit b ↔ qubit 13-b
    float H = 1.0f;
#pragma unroll
    for (int q = 0; q < 8; ++q) H *= ((tid >> (7 - q)) & 1) ? ssiL[q] : sciL[q];
    float p2[4], p4[16], hh[4];
#pragma unroll
    for (int j = 0; j < 4; ++j) p2[j] = ((j & 1) ? ssiL[13] : sciL[13]) * ((j & 2) ? ssiL[12] : sciL[12]);
#pragma unroll
    for (int j = 0; j < 16; ++j) p4[j] = p2[j & 3] * ((j & 4) ? ssiL[11] : sciL[11]) * ((j & 8) ? ssiL[10] : sciL[10]);
#pragma unroll
    for (int j = 0; j < 4; ++j) hh[j] = H * ((j & 1) ? ssiL[9] : sciL[9]) * ((j & 2) ? ssiL[8] : sciL[8]);
    alignas(16) float rs[64];
#pragma unroll
    for (int r = 0; r < 64; ++r) rs[r] = p4[r & 15] * hh[r >> 4];

    // 15 phases, 3 per layer; transitions stream through the 32KB half-buffer
    run_gates<1, 0>(rs, cst, snt, tid);
    transition<1, 0, 1, 1>(rs, bt, tid); run_gates<1, 1>(rs, cst, snt, tid);
    transition<1, 1, 1, 2>(rs, bt, tid); run_gates<1, 2>(rs, cst, snt, tid);
    transition<1, 2, 2, 0>(rs, bt, tid); run_gates<2, 0>(rs, cst, snt, tid);
    transition<2, 0, 2, 1>(rs, bt, tid); run_gates<2, 1>(rs, cst, snt, tid);
    transition<2, 1, 2, 2>(rs, bt, tid); run_gates<2, 2>(rs, cst, snt, tid);
    transition<2, 2, 3, 0>(rs, bt, tid); run_gates<3, 0>(rs, cst, snt, tid);
    transition<3, 0, 3, 1>(rs, bt, tid); run_gates<3, 1>(rs, cst, snt, tid);
    transition<3, 1, 3, 2>(rs, bt, tid); run_gates<3, 2>(rs, cst, snt, tid);
    transition<3, 2, 4, 0>(rs, bt, tid); run_gates<4, 0>(rs, cst, snt, tid);
    transition<4, 0, 4, 1>(rs, bt, tid); run_gates<4, 1>(rs, cst, snt, tid);
    transition<4, 1, 4, 2>(rs, bt, tid); run_gates<4, 2>(rs, cst, snt, tid);
    transition<4, 2, 5, 0>(rs, bt, tid); run_gates<5, 0>(rs, cst, snt, tid);
    transition<5, 0, 5, 1>(rs, bt, tid); run_gates<5, 1>(rs, cst, snt, tid);
    transition<5, 1, 5, 2>(rs, bt, tid); run_gates<5, 2>(rs, cst, snt, tid);

    // expectations in-register: gout masks = e13/e12 (row13/12 of U^6);
    // layout (5,2) thread-base has no bits >=10 -> sign is compile-time per register
    constexpr uint32_t f0 = mhv<5,2,0>(), f1 = mhv<5,2,1>(), f2 = mhv<5,2,2>(), f3 = mhv<5,2,3>();
    float e0 = 0.0f, e1 = 0.0f;
#pragma unroll
    for (uint32_t r = 0; r < 64; ++r) {
        const uint32_t M = mreg(r, f0, f1, f2, f3);
        const float v = rs[r];
        e0 = fmaf(v, ((M >> 13) & 1u) ? -v : v, e0);
        e1 = fmaf(v, ((M >> 12) & 1u) ? -v : v, e1);
    }
#pragma unroll
    for (int off = 32; off > 0; off >>= 1) {
        e0 += __shfl_down(e0, off);
        e1 += __shfl_down(e1, off);
    }
    const int wid = tid >> 6, lane = tid & 63;
    if (lane == 0) { red0[wid] = e0; red1[wid] = e1; }
    __syncthreads();
    if (tid == 0) {
        out[b * 2 + 0] = red0[0] + red0[1] + red0[2] + red0[3];
        out[b * 2 + 1] = red1[0] + red1[1] + red1[2] + red1[3];
    }
}

extern "C" void kernel_launch(void* const* d_in, const int* in_sizes, int n_in,
                              void* d_out, int out_size, void* d_ws, size_t ws_size,
                              hipStream_t stream) {
    const float* x = (const float*)d_in[0];   // (1024, 14) f32
    const float* w = (const float*)d_in[1];   // (6, 14) f32
    float* out = (float*)d_out;               // (1024, 2) f32
    float* ws = (float*)d_ws;                 // [0..27] min/scale, [32..101] cos, [112..181] sin

    qs_norm_kernel<<<NQ, 256, 0, stream>>>(x, w, ws);
    qs_main_kernel<<<NBATCH, BLOCK, 0, stream>>>(x, w, ws, ws + 32, ws + 112, out);
}

// Round 7
// 67.667 us; speedup vs baseline: 1.2424x; 1.2424x over previous
//
#include <hip/hip_runtime.h>
#include <stdint.h>

#define NQ 14
#define DIM 16384
#define NL 6
#define NBATCH 1024
#define PI_F 3.14159265358979323846f
#define BLOCK 512

// ================= constexpr GF(2) circuit algebra =================
// Verified end-to-end (rounds 2/5: absmax 0.0).  CNOT chain = I+S.
// After l chains, gate on bit p pairs i with i^mcol(l,p); side-0 selected by
// parity(i & grow(l,p)).  Lucas: C(l,k) odd iff (k & ~l)==0.
constexpr uint32_t mcol(int l, int p) {          // column p of (I+S)^l
    uint32_t m = 0;
    for (int k = 0; k <= p; ++k) if ((k & ~l) == 0) m ^= 1u << (p - k);
    return m;
}
constexpr uint32_t grow(int l, int p) {          // row p of U^l = (I+S)^(16-l)
    uint32_t g = 0;
    const int e = 16 - l;
    for (int k = 0; k + p < NQ; ++k) if ((k & ~e) == 0) g ^= 1u << (p + k);
    return g;
}
constexpr uint32_t popb(uint32_t x) { uint32_t c = 0; while (x) { c += x & 1u; x >>= 1; } return c; }
constexpr int msbit(uint32_t m) { int b = 0; while (m >> (b + 1)) ++b; return b; }
constexpr uint32_t PIW(uint32_t x) { return x ^ (((x >> 6) & 7u) << 2); }  // LDS bank swizzle (XOR-linear)

// 4 groups per layer: p ranges {0..4}, {5..7}, {8..10}, {11..13}
template<int GRP> constexpr int pbase()  { return GRP == 0 ? 0 : (GRP == 1 ? 5 : (GRP == 2 ? 8 : 11)); }
template<int GRP> constexpr int ngates() { return GRP == 0 ? 5 : 3; }

// phase basis: {e0,e1} + 3 hi vectors (4-aligned, = gate-mask hi parts)
template<int L, int GRP, int J> constexpr uint32_t mhv() {
    if constexpr (GRP == 0) return mcol(L, 2 + J) & ~3u;          // gates p2,p3,p4
    else return mcol(L, pbase<GRP>() + J) & ~3u;
}
// register-space mask: mreg5(rmv) == full gate mask (register bit2..4 = m0..m2)
template<int L, int GRP, int K> constexpr uint32_t rmv() {
    if constexpr (GRP == 0) {
        if constexpr (K < 2) return mcol(L, K);                   // p0,p1 live in low2
        else return (4u << (K - 2)) | (mcol(L, K) & 3u);
    } else {
        return (4u << K) | (mcol(L, pbase<GRP>() + K) & 3u);
    }
}
constexpr uint32_t mreg5(uint32_t r, uint32_t m0, uint32_t m1, uint32_t m2) {
    uint32_t M = r & 3u;
    if (r & 4u)  M ^= m0;
    if (r & 8u)  M ^= m1;
    if (r & 16u) M ^= m2;
    return M;
}
constexpr uint32_t sgnw32(uint32_t m0, uint32_t m1, uint32_t m2, uint32_t g) {
    uint32_t w = 0;
    for (uint32_t r = 0; r < 32; ++r)
        w |= (popb(mreg5(r, m0, m1, m2) & g) & 1u) << r;
    return w;
}
// tid-parity mask: comp units are {e2..e13} minus the 3 pivot bits {pbase..pbase+2}
template<int GRP> constexpr uint32_t cg_of(uint32_t g) {
    if constexpr (GRP == 0)      return (g >> 5) & 0x1FFu;                          // units e5..e13
    else if constexpr (GRP == 1) return ((g >> 2) & 7u) | (((g >> 8) & 0x3Fu) << 3); // e2..e4,e8..e13
    else if constexpr (GRP == 2) return ((g >> 2) & 0x3Fu) | (((g >> 11) & 7u) << 6);// e2..e7,e11..e13
    else                         return (g >> 2) & 0x1FFu;                          // e2..e10
}
constexpr bool indep5(uint32_t a, uint32_t b, uint32_t c) {
    uint32_t v[5] = {1u, 2u, a, b, c};
    int rank = 0;
    for (int bit = 13; bit >= 0; --bit) {
        int piv = -1;
        for (int i = rank; i < 5; ++i) if ((v[i] >> bit) & 1) { piv = i; break; }
        if (piv < 0) continue;
        uint32_t t = v[piv]; v[piv] = v[rank]; v[rank] = t;
        for (int i = 0; i < 5; ++i) if (i != rank && ((v[i] >> bit) & 1)) v[i] ^= t;
        ++rank;
    }
    return rank == 5;
}

// RAW thread-base element index (un-swizzled); 9 tid bits -> comp unit bits
template<int GRP> __device__ __forceinline__ uint32_t tb_of(uint32_t tid) {
    if constexpr (GRP == 0)      return tid << 5;
    else if constexpr (GRP == 1) return ((tid & 7u) << 2) | ((tid >> 3) << 8);
    else if constexpr (GRP == 2) return ((tid & 63u) << 2) | ((tid >> 6) << 11);
    else                         return tid << 2;
}

// ================= register-space gate (all compile-time) =================
template<uint32_t RM, uint32_t SG>
__device__ __forceinline__ void gate32(float (&rs)[32], float c, float svp) {
    constexpr uint32_t HB = 1u << msbit(RM);
#pragma unroll
    for (uint32_t r = 0; r < 32; ++r) {
        if ((r & HB) == 0u) {
            const float sv = ((SG >> r) & 1u) ? -svp : svp;   // compile-time select
            const float u = rs[r], v = rs[r ^ RM];
            const float t0 = sv * v;
            const float t1 = sv * u;
            rs[r]      = fmaf(c, u, -t0);   // side0' = c*s0 - s*s1
            rs[r ^ RM] = fmaf(c, v,  t1);   // side1' = c*s1 + s*s0
        }
    }
}

template<int L, int GRP, int K>
__device__ __forceinline__ void gates_rec(float (&rs)[32], const float* __restrict__ cst,
                                          const float* __restrict__ snt, int tid) {
    if constexpr (K < ngates<GRP>()) {
        constexpr int p = pbase<GRP>() + K;
        constexpr uint32_t g  = grow(L, p);
        constexpr uint32_t RM = rmv<L, GRP, K>();
        constexpr uint32_t SG = sgnw32(mhv<L,GRP,0>(), mhv<L,GRP,1>(), mhv<L,GRP,2>(), g);
        constexpr uint32_t CG = cg_of<GRP>(g);
        constexpr int widx = (L - 1) * NQ + (13 - p);
        const float c = cst[widx];
        const float s = snt[widx];
        const float svp = (__popc((uint32_t)tid & CG) & 1) ? -s : s;
        gate32<RM, SG>(rs, c, svp);
        gates_rec<L, GRP, K + 1>(rs, cst, snt, tid);
    }
}

template<int L, int GRP>
__device__ __forceinline__ void run_gates(float (&rs)[32], const float* __restrict__ cst,
                                          const float* __restrict__ snt, int tid) {
    static_assert(indep5(mhv<L,GRP,0>(), mhv<L,GRP,1>(), mhv<L,GRP,2>()), "basis rank");
    gates_rec<L, GRP, 0>(rs, cst, snt, tid);
}

template<int L, int GRP, bool WR>
__device__ __forceinline__ void lds_io(float (&rs)[32], float* st, int tid) {
    constexpr uint32_t m0 = mhv<L,GRP,0>(), m1 = mhv<L,GRP,1>(), m2 = mhv<L,GRP,2>();
    const uint32_t ptw = PIW(tb_of<GRP>((uint32_t)tid));
#pragma unroll
    for (uint32_t gq = 0; gq < 8; ++gq) {
        const uint32_t K = ((gq & 1) ? m0 : 0u) ^ ((gq & 2) ? m1 : 0u) ^ ((gq & 4) ? m2 : 0u);
        const uint32_t a = ptw ^ PIW(K);                        // PIW(K) folds (PIW is XOR-linear)
        if constexpr (WR) *reinterpret_cast<float4*>(st + a) = *reinterpret_cast<const float4*>(&rs[gq * 4]);
        else *reinterpret_cast<float4*>(&rs[gq * 4]) = *reinterpret_cast<const float4*>(st + a);
    }
}

template<int L, int GRP>
__device__ __forceinline__ void mid_phase(float (&rs)[32], float* st,
        const float* __restrict__ cst, const float* __restrict__ snt, int tid) {
    lds_io<L, GRP, false>(rs, st, tid);
    run_gates<L, GRP>(rs, cst, snt, tid);
    lds_io<L, GRP, true>(rs, st, tid);
    __syncthreads();
}

// ================= prepass: min/scale + gate cos/sin tables =================
__global__ __launch_bounds__(256) void qs_norm_kernel(const float* __restrict__ x,
                                                      const float* __restrict__ w,
                                                      float* __restrict__ ws) {
    const int q = blockIdx.x;
    const int tid = threadIdx.x;
    float mn = 3.0e38f, mx = -3.0e38f;
    for (int r = tid; r < NBATCH; r += 256) {
        const float v = x[r * NQ + q];
        mn = fminf(mn, v);
        mx = fmaxf(mx, v);
    }
#pragma unroll
    for (int off = 32; off > 0; off >>= 1) {
        mn = fminf(mn, __shfl_down(mn, off));
        mx = fmaxf(mx, __shfl_down(mx, off));
    }
    __shared__ float smn[4], smx[4];
    const int wid = tid >> 6, lane = tid & 63;
    if (lane == 0) { smn[wid] = mn; smx[wid] = mx; }
    __syncthreads();
    if (tid == 0) {
        mn = fminf(fminf(smn[0], smn[1]), fminf(smn[2], smn[3]));
        mx = fmaxf(fmaxf(smx[0], smx[1]), fmaxf(smx[2], smx[3]));
        ws[q] = mn;
        ws[NQ + q] = PI_F / (mx - mn + 1e-8f);
    }
    if (blockIdx.x == 0) {
        for (int t = tid; t < (NL - 1) * NQ; t += 256) {
            const float h = 0.5f * w[NQ + t];
            ws[32 + t]  = cosf(h);
            ws[112 + t] = sinf(h);
        }
    }
}

// ================= main: one block (512 threads) per batch element =================
__global__ __launch_bounds__(BLOCK, 4) void qs_main_kernel(
        const float* __restrict__ x, const float* __restrict__ w,
        const float* __restrict__ nrm, const float* __restrict__ cst,
        const float* __restrict__ snt, float* __restrict__ out) {
    __shared__ __align__(16) float st[DIM];
    __shared__ float sciL[NQ], ssiL[NQ];
    __shared__ float red0[8], red1[8];
    const int tid = threadIdx.x;
    const int b = blockIdx.x;

    // merged encoding + layer-0 angles, once per block (broadcast via LDS)
    if (tid < NQ) {
        const float ang = (x[b * NQ + tid] - nrm[tid]) * nrm[NQ + tid] + w[tid];
        const float h = 0.5f * ang;
        sciL[tid] = cosf(h);
        ssiL[tid] = sinf(h);
    }
    __syncthreads();

    // product state directly in registers, layout (1,0):
    // element i = tb ^ mreg5(r) with tb = tid<<5; element bit b <-> qubit 13-b
    float H = 1.0f;
#pragma unroll
    for (int j = 0; j < 9; ++j) H *= ((tid >> j) & 1) ? ssiL[8 - j] : sciL[8 - j];
    float A[4], B[8], HB[8];
#pragma unroll
    for (int a = 0; a < 4; ++a)
        A[a] = ((a & 1) ? ssiL[13] : sciL[13]) * ((a & 2) ? ssiL[12] : sciL[12]);
#pragma unroll
    for (int rh = 0; rh < 8; ++rh) {
        const uint32_t Mhi = ((rh & 1) ? 4u : 0u) ^ ((rh & 2) ? 12u : 0u) ^ ((rh & 4) ? 24u : 0u);
        B[rh] = ((Mhi >> 2) & 1 ? ssiL[11] : sciL[11]) *
                ((Mhi >> 3) & 1 ? ssiL[10] : sciL[10]) *
                ((Mhi >> 4) & 1 ? ssiL[9]  : sciL[9]);
        HB[rh] = H * B[rh];
    }
    alignas(16) float rs[32];
#pragma unroll
    for (int r = 0; r < 32; ++r) rs[r] = A[r & 3] * HB[r >> 2];

    // 20 phases, 4 per layer; first has no read, last has no write
    run_gates<1, 0>(rs, cst, snt, tid); lds_io<1, 0, true>(rs, st, tid); __syncthreads();
    mid_phase<1, 1>(rs, st, cst, snt, tid);
    mid_phase<1, 2>(rs, st, cst, snt, tid);
    mid_phase<1, 3>(rs, st, cst, snt, tid);
    mid_phase<2, 0>(rs, st, cst, snt, tid);
    mid_phase<2, 1>(rs, st, cst, snt, tid);
    mid_phase<2, 2>(rs, st, cst, snt, tid);
    mid_phase<2, 3>(rs, st, cst, snt, tid);
    mid_phase<3, 0>(rs, st, cst, snt, tid);
    mid_phase<3, 1>(rs, st, cst, snt, tid);
    mid_phase<3, 2>(rs, st, cst, snt, tid);
    mid_phase<3, 3>(rs, st, cst, snt, tid);
    mid_phase<4, 0>(rs, st, cst, snt, tid);
    mid_phase<4, 1>(rs, st, cst, snt, tid);
    mid_phase<4, 2>(rs, st, cst, snt, tid);
    mid_phase<4, 3>(rs, st, cst, snt, tid);
    mid_phase<5, 0>(rs, st, cst, snt, tid);
    mid_phase<5, 1>(rs, st, cst, snt, tid);
    mid_phase<5, 2>(rs, st, cst, snt, tid);
    lds_io<5, 3, false>(rs, st, tid);
    run_gates<5, 3>(rs, cst, snt, tid);

    // expectations in-register: gout = e13/e12 (rows 13/12 of U^6);
    // layout (5,3) thread-base has no bits >=11 -> sign compile-time per register
    constexpr uint32_t f0 = mhv<5,3,0>(), f1 = mhv<5,3,1>(), f2 = mhv<5,3,2>();
    float e0 = 0.0f, e1 = 0.0f;
#pragma unroll
    for (uint32_t r = 0; r < 32; ++r) {
        const uint32_t M = mreg5(r, f0, f1, f2);
        const float v = rs[r];
        e0 = fmaf(v, ((M >> 13) & 1u) ? -v : v, e0);
        e1 = fmaf(v, ((M >> 12) & 1u) ? -v : v, e1);
    }
#pragma unroll
    for (int off = 32; off > 0; off >>= 1) {
        e0 += __shfl_down(e0, off);
        e1 += __shfl_down(e1, off);
    }
    const int wid = tid >> 6, lane = tid & 63;
    if (lane == 0) { red0[wid] = e0; red1[wid] = e1; }
    __syncthreads();
    if (tid == 0) {
        float a0 = 0.0f, a1 = 0.0f;
#pragma unroll
        for (int i = 0; i < 8; ++i) { a0 += red0[i]; a1 += red1[i]; }
        out[b * 2 + 0] = a0;
        out[b * 2 + 1] = a1;
    }
}

extern "C" void kernel_launch(void* const* d_in, const int* in_sizes, int n_in,
                              void* d_out, int out_size, void* d_ws, size_t ws_size,
                              hipStream_t stream) {
    const float* x = (const float*)d_in[0];   // (1024, 14) f32
    const float* w = (const float*)d_in[1];   // (6, 14) f32
    float* out = (float*)d_out;               // (1024, 2) f32
    float* ws = (float*)d_ws;                 // [0..27] min/scale, [32..101] cos, [112..181] sin

    qs_norm_kernel<<<NQ, 256, 0, stream>>>(x, w, ws);
    qs_main_kernel<<<NBATCH, BLOCK, 0, stream>>>(x, w, ws, ws + 32, ws + 112, out);
}

// Round 8
// 67.623 us; speedup vs baseline: 1.2432x; 1.0007x over previous
//
#include <hip/hip_runtime.h>
#include <stdint.h>

#define NQ 14
#define DIM 16384
#define NL 6
#define NBATCH 1024
#define PI_F 3.14159265358979323846f
#define BLOCK 512

typedef float f32x2 __attribute__((ext_vector_type(2)));

__device__ __forceinline__ f32x2 swap2(f32x2 v) { return __builtin_shufflevector(v, v, 1, 0); }
__device__ __forceinline__ f32x2 fma2(f32x2 a, f32x2 b, f32x2 c) { return __builtin_elementwise_fma(a, b, c); }

// ================= constexpr GF(2) circuit algebra =================
// Verified end-to-end (rounds 2/5/7: absmax 0.0).  CNOT chain = I+S.
// After l chains, gate on bit p pairs i with i^mcol(l,p); side-0 selected by
// parity(i & grow(l,p)).  Lucas: C(l,k) odd iff (k & ~l)==0.
constexpr uint32_t mcol(int l, int p) {          // column p of (I+S)^l
    uint32_t m = 0;
    for (int k = 0; k <= p; ++k) if ((k & ~l) == 0) m ^= 1u << (p - k);
    return m;
}
constexpr uint32_t grow(int l, int p) {          // row p of U^l = (I+S)^(16-l)
    uint32_t g = 0;
    const int e = 16 - l;
    for (int k = 0; k + p < NQ; ++k) if ((k & ~e) == 0) g ^= 1u << (p + k);
    return g;
}
constexpr uint32_t popb(uint32_t x) { uint32_t c = 0; while (x) { c += x & 1u; x >>= 1; } return c; }
constexpr int msbit(uint32_t m) { int b = 0; while (m >> (b + 1)) ++b; return b; }
constexpr uint32_t PIW(uint32_t x) { return x ^ (((x >> 6) & 7u) << 2); }  // LDS bank swizzle (XOR-linear)

// 4 groups per layer: p ranges {0..4}, {5..7}, {8..10}, {11..13}
template<int GRP> constexpr int pbase()  { return GRP == 0 ? 0 : (GRP == 1 ? 5 : (GRP == 2 ? 8 : 11)); }
template<int GRP> constexpr int ngates() { return GRP == 0 ? 5 : 3; }

// phase basis: {e0,e1} + 3 hi vectors (4-aligned, = gate-mask hi parts)
template<int L, int GRP, int J> constexpr uint32_t mhv() {
    if constexpr (GRP == 0) return mcol(L, 2 + J) & ~3u;          // gates p2,p3,p4
    else return mcol(L, pbase<GRP>() + J) & ~3u;
}
// register-space mask: mreg5(rmv) == full gate mask (register bit2..4 = m0..m2)
template<int L, int GRP, int K> constexpr uint32_t rmv() {
    if constexpr (GRP == 0) {
        if constexpr (K < 2) return mcol(L, K);                   // p0,p1 live in low2
        else return (4u << (K - 2)) | (mcol(L, K) & 3u);
    } else {
        return (4u << K) | (mcol(L, pbase<GRP>() + K) & 3u);
    }
}
constexpr uint32_t mreg5(uint32_t r, uint32_t m0, uint32_t m1, uint32_t m2) {
    uint32_t M = r & 3u;
    if (r & 4u)  M ^= m0;
    if (r & 8u)  M ^= m1;
    if (r & 16u) M ^= m2;
    return M;
}
constexpr uint32_t sgnw32(uint32_t m0, uint32_t m1, uint32_t m2, uint32_t g) {
    uint32_t w = 0;
    for (uint32_t r = 0; r < 32; ++r)
        w |= (popb(mreg5(r, m0, m1, m2) & g) & 1u) << r;
    return w;
}
// tid-parity mask: comp units are {e2..e13} minus the 3 pivot bits {pbase..pbase+2}
template<int GRP> constexpr uint32_t cg_of(uint32_t g) {
    if constexpr (GRP == 0)      return (g >> 5) & 0x1FFu;                          // units e5..e13
    else if constexpr (GRP == 1) return ((g >> 2) & 7u) | (((g >> 8) & 0x3Fu) << 3); // e2..e4,e8..e13
    else if constexpr (GRP == 2) return ((g >> 2) & 0x3Fu) | (((g >> 11) & 7u) << 6);// e2..e7,e11..e13
    else                         return (g >> 2) & 0x1FFu;                          // e2..e10
}
constexpr bool indep5(uint32_t a, uint32_t b, uint32_t c) {
    uint32_t v[5] = {1u, 2u, a, b, c};
    int rank = 0;
    for (int bit = 13; bit >= 0; --bit) {
        int piv = -1;
        for (int i = rank; i < 5; ++i) if ((v[i] >> bit) & 1) { piv = i; break; }
        if (piv < 0) continue;
        uint32_t t = v[piv]; v[piv] = v[rank]; v[rank] = t;
        for (int i = 0; i < 5; ++i) if (i != rank && ((v[i] >> bit) & 1)) v[i] ^= t;
        ++rank;
    }
    return rank == 5;
}

// RAW thread-base element index (un-swizzled); 9 tid bits -> comp unit bits
template<int GRP> __device__ __forceinline__ uint32_t tb_of(uint32_t tid) {
    if constexpr (GRP == 0)      return tid << 5;
    else if constexpr (GRP == 1) return ((tid & 7u) << 2) | ((tid >> 3) << 8);
    else if constexpr (GRP == 2) return ((tid & 63u) << 2) | ((tid >> 6) << 11);
    else                         return tid << 2;
}

// ================= packed register-space gate (all indices compile-time) =================
// State: f32x2 rs[16]; lane (x/y) = old register bit0, pair-index R = old bits 1..4.
// Old scalar form (rounds 5/7, absmax 0.0):
//   sv = SGbit(r) ? -svp : svp;  rs[r] = c*u - sv*v;  rs[r^RM] = c*v + sv*u
// Packed: psv(b)=+sv=b?nsv:svp, msv(b)=-sv=b?svp:nsv — negation exact, bit-identical.
#define PSVf(b) ((b) ? nsv : svp)
#define MSVf(b) ((b) ? svp : nsv)
template<uint32_t RM, uint32_t SG>
__device__ __forceinline__ void gate_pk(f32x2 (&rs)[16], f32x2 cc, float svp, float nsv) {
    if constexpr (RM == 1u) {
        // partner = other lane of same register pair
#pragma unroll
        for (uint32_t R = 0; R < 16; ++R) {
            const uint32_t b = (SG >> (2u * R)) & 1u;
            const f32x2 vA = rs[R];
            f32x2 sg; sg.x = MSVf(b); sg.y = PSVf(b);
            rs[R] = fma2(cc, vA, sg * swap2(vA));
        }
    } else if constexpr ((RM & 1u) == 0u) {
        constexpr uint32_t RMp = RM >> 1;
        constexpr uint32_t HBp = 1u << (msbit(RM) - 1);
#pragma unroll
        for (uint32_t R = 0; R < 16; ++R) {
            if ((R & HBp) == 0u) {
                const uint32_t b0 = (SG >> (2u * R)) & 1u;
                const uint32_t b1 = (SG >> (2u * R + 1u)) & 1u;
                const f32x2 vA = rs[R], vB = rs[R ^ RMp];
                f32x2 mv; mv.x = MSVf(b0); mv.y = MSVf(b1);
                f32x2 pv; pv.x = PSVf(b0); pv.y = PSVf(b1);
                rs[R]       = fma2(cc, vA, mv * vB);
                rs[R ^ RMp] = fma2(cc, vB, pv * vA);
            }
        }
    } else {
        // bit0 set, RM > 1: partner = swapped lanes of rs[R ^ (RM>>1)]
        constexpr uint32_t RMp = RM >> 1;
        constexpr uint32_t HBp = 1u << (msbit(RM) - 1);
#pragma unroll
        for (uint32_t R = 0; R < 16; ++R) {
            if ((R & HBp) == 0u) {
                const uint32_t b0 = (SG >> (2u * R)) & 1u;
                const uint32_t b1 = (SG >> (2u * R + 1u)) & 1u;
                const f32x2 vA = rs[R], vB = rs[R ^ RMp];
                f32x2 mv; mv.x = MSVf(b0); mv.y = MSVf(b1);
                f32x2 pv; pv.x = PSVf(b1); pv.y = PSVf(b0);   // pair signs swap with lanes
                rs[R]       = fma2(cc, vA, mv * swap2(vB));
                rs[R ^ RMp] = fma2(cc, vB, pv * swap2(vA));
            }
        }
    }
}
#undef PSVf
#undef MSVf

template<int L, int GRP, int K>
__device__ __forceinline__ void gates_rec(f32x2 (&rs)[16], const float* __restrict__ cst,
                                          const float* __restrict__ snt, int tid) {
    if constexpr (K < ngates<GRP>()) {
        constexpr int p = pbase<GRP>() + K;
        constexpr uint32_t g  = grow(L, p);
        constexpr uint32_t RM = rmv<L, GRP, K>();
        constexpr uint32_t SG = sgnw32(mhv<L,GRP,0>(), mhv<L,GRP,1>(), mhv<L,GRP,2>(), g);
        constexpr uint32_t CG = cg_of<GRP>(g);
        constexpr int widx = (L - 1) * NQ + (13 - p);
        const float c = cst[widx];
        const float s = snt[widx];
        const float svp = (__popc((uint32_t)tid & CG) & 1) ? -s : s;
        const float nsv = -svp;
        f32x2 cc; cc.x = c; cc.y = c;
        gate_pk<RM, SG>(rs, cc, svp, nsv);
        gates_rec<L, GRP, K + 1>(rs, cst, snt, tid);
    }
}

template<int L, int GRP>
__device__ __forceinline__ void run_gates(f32x2 (&rs)[16], const float* __restrict__ cst,
                                          const float* __restrict__ snt, int tid) {
    static_assert(indep5(mhv<L,GRP,0>(), mhv<L,GRP,1>(), mhv<L,GRP,2>()), "basis rank");
    gates_rec<L, GRP, 0>(rs, cst, snt, tid);
}

template<int L, int GRP, bool WR>
__device__ __forceinline__ void lds_io(f32x2 (&rs)[16], float* st, int tid) {
    constexpr uint32_t m0 = mhv<L,GRP,0>(), m1 = mhv<L,GRP,1>(), m2 = mhv<L,GRP,2>();
    const uint32_t ptw = PIW(tb_of<GRP>((uint32_t)tid));
    float4* rq = reinterpret_cast<float4*>(rs);
#pragma unroll
    for (uint32_t gq = 0; gq < 8; ++gq) {
        const uint32_t K = ((gq & 1) ? m0 : 0u) ^ ((gq & 2) ? m1 : 0u) ^ ((gq & 4) ? m2 : 0u);
        const uint32_t a = ptw ^ PIW(K);                        // PIW(K) folds (PIW is XOR-linear)
        if constexpr (WR) *reinterpret_cast<float4*>(st + a) = rq[gq];
        else rq[gq] = *reinterpret_cast<const float4*>(st + a);
    }
}

template<int L, int GRP>
__device__ __forceinline__ void mid_phase(f32x2 (&rs)[16], float* st,
        const float* __restrict__ cst, const float* __restrict__ snt, int tid) {
    lds_io<L, GRP, false>(rs, st, tid);
    run_gates<L, GRP>(rs, cst, snt, tid);
    lds_io<L, GRP, true>(rs, st, tid);
    __syncthreads();
}

// ================= prepass: min/scale + gate cos/sin tables =================
__global__ __launch_bounds__(256) void qs_norm_kernel(const float* __restrict__ x,
                                                      const float* __restrict__ w,
                                                      float* __restrict__ ws) {
    const int q = blockIdx.x;
    const int tid = threadIdx.x;
    float mn = 3.0e38f, mx = -3.0e38f;
    for (int r = tid; r < NBATCH; r += 256) {
        const float v = x[r * NQ + q];
        mn = fminf(mn, v);
        mx = fmaxf(mx, v);
    }
#pragma unroll
    for (int off = 32; off > 0; off >>= 1) {
        mn = fminf(mn, __shfl_down(mn, off));
        mx = fmaxf(mx, __shfl_down(mx, off));
    }
    __shared__ float smn[4], smx[4];
    const int wid = tid >> 6, lane = tid & 63;
    if (lane == 0) { smn[wid] = mn; smx[wid] = mx; }
    __syncthreads();
    if (tid == 0) {
        mn = fminf(fminf(smn[0], smn[1]), fminf(smn[2], smn[3]));
        mx = fmaxf(fmaxf(smx[0], smx[1]), fmaxf(smx[2], smx[3]));
        ws[q] = mn;
        ws[NQ + q] = PI_F / (mx - mn + 1e-8f);
    }
    if (blockIdx.x == 0) {
        for (int t = tid; t < (NL - 1) * NQ; t += 256) {
            const float h = 0.5f * w[NQ + t];
            ws[32 + t]  = cosf(h);
            ws[112 + t] = sinf(h);
        }
    }
}

// ================= main: one block (512 threads) per batch element =================
__global__ __launch_bounds__(BLOCK, 4) void qs_main_kernel(
        const float* __restrict__ x, const float* __restrict__ w,
        const float* __restrict__ nrm, const float* __restrict__ cst,
        const float* __restrict__ snt, float* __restrict__ out) {
    __shared__ __align__(16) float st[DIM];
    __shared__ float sciL[NQ], ssiL[NQ];
    __shared__ float red0[8], red1[8];
    const int tid = threadIdx.x;
    const int b = blockIdx.x;

    // merged encoding + layer-0 angles, once per block (broadcast via LDS)
    if (tid < NQ) {
        const float ang = (x[b * NQ + tid] - nrm[tid]) * nrm[NQ + tid] + w[tid];
        const float h = 0.5f * ang;
        sciL[tid] = cosf(h);
        ssiL[tid] = sinf(h);
    }
    __syncthreads();

    // product state directly in registers, layout (1,0):
    // element i = tb ^ mreg5(r) with tb = tid<<5; element bit b <-> qubit 13-b
    float H = 1.0f;
#pragma unroll
    for (int j = 0; j < 9; ++j) H *= ((tid >> j) & 1) ? ssiL[8 - j] : sciL[8 - j];
    float A4[4], HB8[8];
#pragma unroll
    for (int a = 0; a < 4; ++a)
        A4[a] = ((a & 1) ? ssiL[13] : sciL[13]) * ((a & 2) ? ssiL[12] : sciL[12]);
#pragma unroll
    for (int rh = 0; rh < 8; ++rh) {
        const uint32_t Mhi = ((rh & 1) ? 4u : 0u) ^ ((rh & 2) ? 12u : 0u) ^ ((rh & 4) ? 24u : 0u);
        HB8[rh] = H * ((Mhi >> 2) & 1 ? ssiL[11] : sciL[11]) *
                      ((Mhi >> 3) & 1 ? ssiL[10] : sciL[10]) *
                      ((Mhi >> 4) & 1 ? ssiL[9]  : sciL[9]);
    }
    alignas(16) f32x2 rs[16];
#pragma unroll
    for (int R = 0; R < 16; ++R) {
        const int a0 = (R & 1) * 2;
        f32x2 v; v.x = A4[a0]; v.y = A4[a0 + 1];
        rs[R] = v * HB8[R >> 1];
    }

    // 20 phases, 4 per layer; first has no read, last has no write
    run_gates<1, 0>(rs, cst, snt, tid); lds_io<1, 0, true>(rs, st, tid); __syncthreads();
    mid_phase<1, 1>(rs, st, cst, snt, tid);
    mid_phase<1, 2>(rs, st, cst, snt, tid);
    mid_phase<1, 3>(rs, st, cst, snt, tid);
    mid_phase<2, 0>(rs, st, cst, snt, tid);
    mid_phase<2, 1>(rs, st, cst, snt, tid);
    mid_phase<2, 2>(rs, st, cst, snt, tid);
    mid_phase<2, 3>(rs, st, cst, snt, tid);
    mid_phase<3, 0>(rs, st, cst, snt, tid);
    mid_phase<3, 1>(rs, st, cst, snt, tid);
    mid_phase<3, 2>(rs, st, cst, snt, tid);
    mid_phase<3, 3>(rs, st, cst, snt, tid);
    mid_phase<4, 0>(rs, st, cst, snt, tid);
    mid_phase<4, 1>(rs, st, cst, snt, tid);
    mid_phase<4, 2>(rs, st, cst, snt, tid);
    mid_phase<4, 3>(rs, st, cst, snt, tid);
    mid_phase<5, 0>(rs, st, cst, snt, tid);
    mid_phase<5, 1>(rs, st, cst, snt, tid);
    mid_phase<5, 2>(rs, st, cst, snt, tid);
    lds_io<5, 3, false>(rs, st, tid);
    run_gates<5, 3>(rs, cst, snt, tid);

    // expectations in-register: gout = e13/e12 (rows 13/12 of U^6);
    // layout (5,3) thread-base has no bits >=11 -> sign compile-time per register
    constexpr uint32_t f0 = mhv<5,3,0>(), f1 = mhv<5,3,1>(), f2 = mhv<5,3,2>();
    const float* rsf = reinterpret_cast<const float*>(rs);
    float e0 = 0.0f, e1 = 0.0f;
#pragma unroll
    for (uint32_t r = 0; r < 32; ++r) {
        const uint32_t M = mreg5(r, f0, f1, f2);
        const float v = rsf[r];
        e0 = fmaf(v, ((M >> 13) & 1u) ? -v : v, e0);
        e1 = fmaf(v, ((M >> 12) & 1u) ? -v : v, e1);
    }
#pragma unroll
    for (int off = 32; off > 0; off >>= 1) {
        e0 += __shfl_down(e0, off);
        e1 += __shfl_down(e1, off);
    }
    const int wid = tid >> 6, lane = tid & 63;
    if (lane == 0) { red0[wid] = e0; red1[wid] = e1; }
    __syncthreads();
    if (tid == 0) {
        float a0 = 0.0f, a1 = 0.0f;
#pragma unroll
        for (int i = 0; i < 8; ++i) { a0 += red0[i]; a1 += red1[i]; }
        out[b * 2 + 0] = a0;
        out[b * 2 + 1] = a1;
    }
}

extern "C" void kernel_launch(void* const* d_in, const int* in_sizes, int n_in,
                              void* d_out, int out_size, void* d_ws, size_t ws_size,
                              hipStream_t stream) {
    const float* x = (const float*)d_in[0];   // (1024, 14) f32
    const float* w = (const float*)d_in[1];   // (6, 14) f32
    float* out = (float*)d_out;               // (1024, 2) f32
    float* ws = (float*)d_ws;                 // [0..27] min/scale, [32..101] cos, [112..181] sin

    qs_norm_kernel<<<NQ, 256, 0, stream>>>(x, w, ws);
    qs_main_kernel<<<NBATCH, BLOCK, 0, stream>>>(x, w, ws, ws + 32, ws + 112, out);
}